// Round 1
// baseline (35.331 us; speedup 1.0000x reference)
//
#include <hip/hip_runtime.h>

#define HH 352
#define WW 1216
#define NBOX 16
#define KCAND 61
#define SLICES 16
#define HN 88    // H/4
#define WN 304   // W/4
#define THREADS 256

// Kernel 1: per (slice, box) block — accumulate 61 candidate losses over the
// block's strided rows of the box region. Deterministic (no atomics).
__global__ __launch_bounds__(THREADS) void loss_partial_kernel(
    const float* __restrict__ nocs,    // (3, HN, WN)
    const float* __restrict__ dd,      // (HH, WW, 3)
    const int*   __restrict__ boxes,   // (N, 4)
    const float* __restrict__ pc,      // (N, 2)
    const float* __restrict__ bdepth,  // (N,)
    const float* __restrict__ intr,    // (3,3)
    float* __restrict__ partial,       // (N, S, K)
    int S)
{
    const int box   = blockIdx.y;
    const int slice = blockIdx.x;
    const int tid   = threadIdx.x;

    const int x1 = boxes[box*4+0], y1 = boxes[box*4+1];
    const int x2 = boxes[box*4+2], y2 = boxes[box*4+3];
    const float fx = intr[0], cx = intr[2], fy = intr[4], cy = intr[5];
    const float ax = (pc[box*2+0] - cx) / fx;
    const float ay = (pc[box*2+1] - cy) / fy;
    const float bd = bdepth[box];

    float acc[KCAND];
#pragma unroll
    for (int k = 0; k < KCAND; ++k) acc[k] = 0.f;

    for (int row = y1 + slice; row < y2; row += S) {
        // bilinear y setup (half-pixel, 4x upsample): frac from row&3
        const int ry  = row & 3;
        const int ym  = row >> 2;
        const int yy0 = ym + ((ry >= 2) ? 0 : -1);
        const float wy = 0.125f + 0.25f * (float)((ry + 2) & 3);
        const int ya = max(yy0, 0);
        const int yb = min(yy0 + 1, HN - 1);

        for (int x = x1 + tid; x < x2; x += THREADS) {
            const float* dp = dd + ((size_t)row * WW + x) * 3;
            const float dz = dp[2];
            if (dz < 1.0f) continue;  // empty mask

            const int rx  = x & 3;
            const int xm  = x >> 2;
            const int xx0 = xm + ((rx >= 2) ? 0 : -1);
            const float wx = 0.125f + 0.25f * (float)((rx + 2) & 3);
            const int xa = max(xx0, 0);
            const int xb = min(xx0 + 1, WN - 1);

            float b[3];
#pragma unroll
            for (int c = 0; c < 3; ++c) {
                const float* np_ = nocs + c * (HN * WN);
                const float v00 = np_[ya*WN + xa], v01 = np_[ya*WN + xb];
                const float v10 = np_[yb*WN + xa], v11 = np_[yb*WN + xb];
                const float v0 = v00 + (v01 - v00) * wx;
                const float v1 = v10 + (v11 - v10) * wx;
                const float nup = v0 + (v1 - v0) * wy;
                b[c] = nup - dp[c];
            }
#pragma unroll
            for (int k = 0; k < KCAND; ++k) {
                const float dk = bd + (0.1f * (float)k - 3.0f);
                acc[k] += fabsf(fmaf(ax, dk, b[0]))
                        + fabsf(fmaf(ay, dk, b[1]))
                        + fabsf(b[2] + dk);
            }
        }
    }

    // block reduce: wave shuffle, then 4-wave sum in fixed order
    const int lane = tid & 63;
    const int wave = tid >> 6;
    __shared__ float wbuf[THREADS / 64][KCAND];
#pragma unroll
    for (int k = 0; k < KCAND; ++k) {
        float v = acc[k];
        for (int off = 32; off; off >>= 1) v += __shfl_xor(v, off, 64);
        if (lane == 0) wbuf[wave][k] = v;
    }
    __syncthreads();
    if (tid < KCAND) {
        float s = wbuf[0][tid] + wbuf[1][tid] + wbuf[2][tid] + wbuf[3][tid];
        partial[((size_t)box * S + slice) * KCAND + tid] = s;
    }
}

// Kernel 2: per-box argmin over K (first-index tie-break) + output write.
__global__ __launch_bounds__(64) void finalize_kernel(
    const float* __restrict__ partial,  // (N, S, K)
    const float* __restrict__ pc,
    const float* __restrict__ bdepth,
    const float* __restrict__ dims,     // (N,3)
    const float* __restrict__ intr,
    float* __restrict__ out,            // (N,3)
    int S)
{
    const int box  = blockIdx.x;
    const int lane = threadIdx.x;

    float loss = INFINITY;
    int kk = lane;
    if (lane < KCAND) {
        float s = 0.f;
        for (int sl = 0; sl < S; ++sl)
            s += partial[((size_t)box * S + sl) * KCAND + lane];
        loss = s;
    }
    // wave argmin, ties -> smaller k (matches jnp.argmin first occurrence)
    for (int off = 1; off < 64; off <<= 1) {
        const float ol = __shfl_xor(loss, off, 64);
        const int   ok = __shfl_xor(kk,   off, 64);
        if (ol < loss || (ol == loss && ok < kk)) { loss = ol; kk = ok; }
    }
    if (lane == 0) {
        const float fx = intr[0], cx = intr[2], fy = intr[4], cy = intr[5];
        const float dk = bdepth[box] + (0.1f * (float)kk - 3.0f);
        const float axv = (pc[box*2+0] - cx) / fx;
        const float ayv = (pc[box*2+1] - cy) / fy;
        out[box*3+0] = axv * dk;
        out[box*3+1] = ayv * dk + dims[box*3+1] * 0.5f;
        out[box*3+2] = dk;
    }
}

extern "C" void kernel_launch(void* const* d_in, const int* in_sizes, int n_in,
                              void* d_out, int out_size, void* d_ws, size_t ws_size,
                              hipStream_t stream) {
    const float* nocs  = (const float*)d_in[0];
    const float* dd    = (const float*)d_in[1];
    const int*   boxes = (const int*)d_in[2];
    const float* pc    = (const float*)d_in[3];
    const float* bd    = (const float*)d_in[4];
    const float* dims  = (const float*)d_in[5];
    const float* intr  = (const float*)d_in[6];
    float* out     = (float*)d_out;
    float* partial = (float*)d_ws;

    int S = SLICES;
    while (S > 1 && (size_t)NBOX * S * KCAND * sizeof(float) > ws_size) S >>= 1;

    loss_partial_kernel<<<dim3(S, NBOX), THREADS, 0, stream>>>(
        nocs, dd, boxes, pc, bd, intr, partial, S);
    finalize_kernel<<<NBOX, 64, 0, stream>>>(
        partial, pc, bd, dims, intr, out, S);
}